// Round 3
// baseline (709.752 us; speedup 1.0000x reference)
//
#include <hip/hip_runtime.h>

// ---------------------------------------------------------------------------
// GraphSAGE 2-layer, bf16 + bucketed CSR build:
//   bucket_hist: per-block LDS histogram of dst>>6 -> bcnt[782]
//   bucket_scan: exclusive scan of bcnt -> bucket_base / bucket_cursor
//   partition:   edges -> per-bucket packed pairs ((dst&63)<<16 | src)
//                (write front = 782 positions => no write amplification)
//   bucket_scatter: 1 workgroup/bucket, LDS node counts + shuffle-scan ->
//                offs/inv_deg/csr (csr writes land in ~8KB local window)
//   agg(xb) -> mean1b ; MFMA gemms ; projection-first layer 2 (unchanged)
// ---------------------------------------------------------------------------

#define IN_DIM 128
#define HID_DIM 256
#define OUT_DIM 128

typedef unsigned short u16;
typedef unsigned int u32;
typedef __attribute__((ext_vector_type(8))) short short8;   // 8 bf16 (4 VGPRs)
typedef __attribute__((ext_vector_type(4))) float float4v;  // 4 fp32 acc

static __device__ __forceinline__ u16 f2bf(float f) {
    u32 u = __builtin_bit_cast(u32, f);
    u = (u + 0x7fffu + ((u >> 16) & 1u)) >> 16;
    return (u16)u;
}
static __device__ __forceinline__ float bf2f(u32 lo16) {
    return __builtin_bit_cast(float, lo16 << 16);
}

// -------------------- bucketed CSR build --------------------
// nodes-per-bucket = 64, bucket(node) = node >> 6

#define EPB 8192  // edges per block in bucket_hist

__global__ __launch_bounds__(256) void bucket_hist(
    const int* __restrict__ dst, int n_edges, int nb, int* __restrict__ bcnt) {
    __shared__ int h[784];
    int t = threadIdx.x;
    for (int i = t; i < nb; i += 256) h[i] = 0;
    __syncthreads();
    int base = blockIdx.x * EPB;
    int end = min(base + EPB, n_edges);
    for (int i = base + t; i < end; i += 256) atomicAdd(&h[dst[i] >> 6], 1);
    __syncthreads();
    for (int i = t; i < nb; i += 256)
        if (h[i]) atomicAdd(&bcnt[i], h[i]);
}

__global__ __launch_bounds__(1024) void bucket_scan(
    const int* __restrict__ bcnt, int nb, int n_edges,
    int* __restrict__ bbase, int* __restrict__ bcur) {
    __shared__ int s[1024];
    int t = threadIdx.x;
    int v = (t < nb) ? bcnt[t] : 0;
    s[t] = v;
    __syncthreads();
    for (int off = 1; off < 1024; off <<= 1) {
        int add = (t >= off) ? s[t - off] : 0;
        __syncthreads();
        s[t] += add;
        __syncthreads();
    }
    if (t < nb) {
        int excl = s[t] - v;
        bbase[t] = excl;
        bcur[t] = excl;
    }
    if (t == 0) bbase[nb] = n_edges;
}

__global__ __launch_bounds__(256) void partition_kernel(
    const int* __restrict__ src, const int* __restrict__ dst, int n_edges,
    int* __restrict__ bcur, u32* __restrict__ pairs) {
    int i = blockIdx.x * blockDim.x + threadIdx.x;
    if (i < n_edges) {
        int d = dst[i];
        int b = d >> 6;
        int pos = atomicAdd(&bcur[b], 1);
        pairs[pos] = ((u32)(d & 63) << 16) | (u32)src[i];
    }
}

__global__ __launch_bounds__(256) void bucket_scatter(
    const u32* __restrict__ pairs, const int* __restrict__ bbase,
    int n_nodes, int n_edges,
    int* __restrict__ offs, float* __restrict__ inv_deg,
    int* __restrict__ csr) {
    int b = blockIdx.x;
    int t = threadIdx.x;
    int beg = bbase[b], end = bbase[b + 1];
    __shared__ int cnt[64];
    __shared__ int cur[64];
    if (t < 64) cnt[t] = 0;
    __syncthreads();
    for (int i = beg + t; i < end; i += 256)
        atomicAdd(&cnt[(pairs[i] >> 16) & 63], 1);
    __syncthreads();
    if (t < 64) {  // wave 0: shuffle exclusive scan over 64 node counts
        int v = cnt[t];
        int incl = v;
#pragma unroll
        for (int off = 1; off < 64; off <<= 1) {
            int u = __shfl_up(incl, off, 64);
            if (t >= off) incl += u;
        }
        int o = beg + incl - v;
        int node = b * 64 + t;
        if (node < n_nodes) {
            offs[node] = o;
            inv_deg[node] = 1.0f / (float)(v > 0 ? v : 1);
        }
        cur[t] = o;
    }
    if (b == 0 && t == 0) offs[n_nodes] = n_edges;
    __syncthreads();
    for (int i = beg + t; i < end; i += 256) {
        u32 pr = pairs[i];
        int p = atomicAdd(&cur[(pr >> 16) & 63], 1);
        csr[p] = (int)(pr & 0xffffu);
    }
}

// -------------------- casts --------------------

__global__ void cast_x_kernel(const float* __restrict__ in,
                              u16* __restrict__ out, int n4) {
    int i = blockIdx.x * 256 + threadIdx.x;
    if (i < n4) {
        float4 v = *(const float4*)(in + (size_t)i * 4);
        u32 lo = (u32)f2bf(v.x) | ((u32)f2bf(v.y) << 16);
        u32 hi = (u32)f2bf(v.z) | ((u32)f2bf(v.w) << 16);
        uint2 o;
        o.x = lo;
        o.y = hi;
        *(uint2*)(out + (size_t)i * 4) = o;
    }
}

// in: [R][C] fp32 row-major -> out: [C][R] bf16 row-major
__global__ void transpose_cast_kernel(const float* __restrict__ in,
                                      u16* __restrict__ out, int R, int C) {
    int i = blockIdx.x * 256 + threadIdx.x;
    if (i < R * C) {
        int c = i / R;
        int r = i - c * R;
        out[i] = f2bf(in[(size_t)r * C + c]);
    }
}

// -------------------- mean aggregation (D=128 bf16, 1 wave/node) -----------

__global__ __launch_bounds__(256) void agg_bf16(
    const u16* __restrict__ feat, const int* __restrict__ offs,
    const int* __restrict__ csr, const float* __restrict__ inv_deg,
    int n_nodes, u16* __restrict__ out_bf, float* __restrict__ out_f) {
    int wave = threadIdx.x >> 6;
    int lane = threadIdx.x & 63;
    int node = blockIdx.x * 4 + wave;
    if (node >= n_nodes) return;
    int beg = offs[node], end = offs[node + 1];
    float a0 = 0.f, a1 = 0.f;
    int i = beg;
    for (; i + 8 <= end; i += 8) {
        u32 v[8];
#pragma unroll
        for (int j = 0; j < 8; j++) {
            int s = csr[i + j];
            v[j] = *(const u32*)(feat + (size_t)s * 128 + lane * 2);
        }
#pragma unroll
        for (int j = 0; j < 8; j++) {
            a0 += bf2f(v[j] & 0xffffu);
            a1 += bf2f(v[j] >> 16);
        }
    }
    for (; i < end; i++) {
        int s = csr[i];
        u32 v = *(const u32*)(feat + (size_t)s * 128 + lane * 2);
        a0 += bf2f(v & 0xffffu);
        a1 += bf2f(v >> 16);
    }
    float inv = inv_deg[node];
    a0 *= inv;
    a1 *= inv;
    if (out_bf) {
        u32 pv = (u32)f2bf(a0) | ((u32)f2bf(a1) << 16);
        *(u32*)(out_bf + (size_t)node * 128 + lane * 2) = pv;
    } else {
        float2 o;
        o.x = a0;
        o.y = a1;
        *(float2*)(out_f + (size_t)node * 128 + lane * 2) = o;
    }
}

// -------------------- MFMA GEMM --------------------
// C[M,N] = act( sum_mat A_mat[M,K] @ B_mat[K,N] + bias + addend )
// A bf16 row-major; BT bf16 = B^T [N][K] row-major. Block: 4 waves;
// tile 128(M) x 64(N); wave = 32x64 via 2x4 of 16x16x32 mfma.

__global__ __launch_bounds__(256) void gemm_bf16(
    const u16* __restrict__ A1, const u16* __restrict__ A2,
    const u16* __restrict__ BT1, const u16* __restrict__ BT2,
    const float* __restrict__ bias, const float* __restrict__ addend,
    u16* __restrict__ out_bf, float* __restrict__ out_f,
    int M, int K, int N, int nmat, int relu) {
    extern __shared__ u16 Bs[];
    const int KP = K + 8;
    int t = threadIdx.x;
    int colbase = blockIdx.y * 64;

    int total8 = nmat * 64 * K / 8;
    for (int c = t; c < total8; c += 256) {
        int flat = c * 8;
        int mat = flat / (64 * K);
        int rem = flat - mat * 64 * K;
        int n = rem / K;
        int k = rem - n * K;
        const u16* srcp = (mat ? BT2 : BT1) + (size_t)(colbase + n) * K + k;
        *(uint4*)(&Bs[mat * 64 * KP + n * KP + k]) = *(const uint4*)srcp;
    }
    __syncthreads();

    int lane = t & 63;
    int wave = t >> 6;
    int quad = lane >> 4;
    int l16 = lane & 15;
    int row_base = blockIdx.x * 128 + wave * 32;

    float4v zero = {0.f, 0.f, 0.f, 0.f};
    float4v acc[2][4];
#pragma unroll
    for (int mi = 0; mi < 2; mi++)
#pragma unroll
        for (int ni = 0; ni < 4; ni++) acc[mi][ni] = zero;

    for (int mat = 0; mat < nmat; mat++) {
        const u16* A = mat ? A2 : A1;
        const u16* Bp = &Bs[mat * 64 * KP];
        for (int ks = 0; ks < (K >> 5); ks++) {
            int k = ks * 32 + quad * 8;
            short8 af[2] = {{0, 0, 0, 0, 0, 0, 0, 0}, {0, 0, 0, 0, 0, 0, 0, 0}};
#pragma unroll
            for (int mi = 0; mi < 2; mi++) {
                int m = row_base + mi * 16 + l16;
                if (m < M) af[mi] = *(const short8*)(A + (size_t)m * K + k);
            }
#pragma unroll
            for (int ni = 0; ni < 4; ni++) {
                short8 bfr = *(const short8*)(Bp + (ni * 16 + l16) * KP + k);
                acc[0][ni] = __builtin_amdgcn_mfma_f32_16x16x32_bf16(
                    af[0], bfr, acc[0][ni], 0, 0, 0);
                acc[1][ni] = __builtin_amdgcn_mfma_f32_16x16x32_bf16(
                    af[1], bfr, acc[1][ni], 0, 0, 0);
            }
        }
    }

#pragma unroll
    for (int mi = 0; mi < 2; mi++) {
#pragma unroll
        for (int r = 0; r < 4; r++) {
            int row = row_base + mi * 16 + quad * 4 + r;
            if (row >= M) continue;
#pragma unroll
            for (int ni = 0; ni < 4; ni++) {
                int col = colbase + ni * 16 + l16;
                float v = acc[mi][ni][r];
                if (bias) v += bias[col];
                if (addend) v += addend[(size_t)row * N + col];
                if (relu) v = fmaxf(v, 0.f);
                if (out_bf)
                    out_bf[(size_t)row * N + col] = f2bf(v);
                else
                    out_f[(size_t)row * N + col] = v;
            }
        }
    }
}

// -------------------- launcher --------------------

extern "C" void kernel_launch(void* const* d_in, const int* in_sizes, int n_in,
                              void* d_out, int out_size, void* d_ws, size_t ws_size,
                              hipStream_t stream) {
    const float* x   = (const float*)d_in[0];
    const int*  eidx = (const int*)d_in[1];
    const float* Wl1 = (const float*)d_in[2];
    const float* bl1 = (const float*)d_in[3];
    const float* Wr1 = (const float*)d_in[4];
    const float* Wl2 = (const float*)d_in[5];
    const float* bl2 = (const float*)d_in[6];
    const float* Wr2 = (const float*)d_in[7];

    int n_nodes = in_sizes[0] / IN_DIM;
    int n_edges = in_sizes[1] / 2;
    const int* src = eidx;
    const int* dst = eidx + n_edges;
    int nb = (n_nodes + 63) / 64;  // buckets of 64 nodes

    char* p = (char*)d_ws;
    auto alloc = [&](size_t bytes) {
        void* q = (void*)p;
        p += (bytes + 255) & ~(size_t)255;
        return q;
    };
    int*   bcnt    = (int*)alloc((size_t)(nb + 1) * 4);
    int*   bbase   = (int*)alloc((size_t)(nb + 1) * 4);
    int*   bcur    = (int*)alloc((size_t)(nb + 1) * 4);
    int*   offs    = (int*)alloc((size_t)(n_nodes + 1) * 4);
    float* inv_deg = (float*)alloc((size_t)n_nodes * 4);
    u32*   pairs   = (u32*)alloc((size_t)n_edges * 4);
    int*   csr     = (int*)alloc((size_t)n_edges * 4);
    u16*   xb      = (u16*)alloc((size_t)n_nodes * IN_DIM * 2);
    u16*   mean1b  = (u16*)alloc((size_t)n_nodes * IN_DIM * 2);
    u16*   hb      = (u16*)alloc((size_t)n_nodes * HID_DIM * 2);
    u16*   pb      = (u16*)alloc((size_t)n_nodes * OUT_DIM * 2);
    float* mean2   = (float*)alloc((size_t)n_nodes * OUT_DIM * 4);
    u16*   WTl1b   = (u16*)alloc((size_t)IN_DIM * HID_DIM * 2);
    u16*   WTr1b   = (u16*)alloc((size_t)IN_DIM * HID_DIM * 2);
    u16*   WTl2b   = (u16*)alloc((size_t)HID_DIM * OUT_DIM * 2);
    u16*   WTr2b   = (u16*)alloc((size_t)HID_DIM * OUT_DIM * 2);

    int eb = (n_edges + 255) / 256;

    // bucketed CSR build
    hipMemsetAsync(bcnt, 0, (size_t)(nb + 1) * 4, stream);
    bucket_hist<<<(n_edges + EPB - 1) / EPB, 256, 0, stream>>>(dst, n_edges, nb, bcnt);
    bucket_scan<<<1, 1024, 0, stream>>>(bcnt, nb, n_edges, bbase, bcur);
    partition_kernel<<<eb, 256, 0, stream>>>(src, dst, n_edges, bcur, pairs);
    bucket_scatter<<<nb, 256, 0, stream>>>(pairs, bbase, n_nodes, n_edges,
                                           offs, inv_deg, csr);

    // casts
    int n4 = n_nodes * IN_DIM / 4;
    cast_x_kernel<<<(n4 + 255) / 256, 256, 0, stream>>>(x, xb, n4);
    int wsz = IN_DIM * HID_DIM;
    transpose_cast_kernel<<<(wsz + 255) / 256, 256, 0, stream>>>(Wl1, WTl1b, IN_DIM, HID_DIM);
    transpose_cast_kernel<<<(wsz + 255) / 256, 256, 0, stream>>>(Wr1, WTr1b, IN_DIM, HID_DIM);
    transpose_cast_kernel<<<(wsz + 255) / 256, 256, 0, stream>>>(Wl2, WTl2b, HID_DIM, OUT_DIM);
    transpose_cast_kernel<<<(wsz + 255) / 256, 256, 0, stream>>>(Wr2, WTr2b, HID_DIM, OUT_DIM);

    int gx = (n_nodes + 127) / 128;

    // layer 1: agg x, h = relu(mean1@Wl1 + x@Wr1 + bl1)
    agg_bf16<<<(n_nodes + 3) / 4, 256, 0, stream>>>(xb, offs, csr, inv_deg,
                                                    n_nodes, mean1b, nullptr);
    {
        dim3 g(gx, HID_DIM / 64);
        size_t smem = 2 * 64 * (size_t)(IN_DIM + 8) * 2;
        gemm_bf16<<<g, 256, smem, stream>>>(mean1b, xb, WTl1b, WTr1b, bl1,
                                            nullptr, hb, nullptr,
                                            n_nodes, IN_DIM, HID_DIM, 2, 1);
    }

    // layer 2 projection-first: pb = hb@Wl2
    {
        dim3 g(gx, OUT_DIM / 64);
        size_t smem = 1 * 64 * (size_t)(HID_DIM + 8) * 2;
        gemm_bf16<<<g, 256, smem, stream>>>(hb, nullptr, WTl2b, nullptr,
                                            nullptr, nullptr, pb, nullptr,
                                            n_nodes, HID_DIM, OUT_DIM, 1, 0);
    }
    // mean2 = mean(pb) (fp32)
    agg_bf16<<<(n_nodes + 3) / 4, 256, 0, stream>>>(pb, offs, csr, inv_deg,
                                                    n_nodes, nullptr, mean2);
    // out = hb@Wr2 + bl2 + mean2
    {
        dim3 g(gx, OUT_DIM / 64);
        size_t smem = 1 * 64 * (size_t)(HID_DIM + 8) * 2;
        gemm_bf16<<<g, 256, smem, stream>>>(hb, nullptr, WTr2b, nullptr,
                                            bl2, mean2, nullptr, (float*)d_out,
                                            n_nodes, HID_DIM, OUT_DIM, 1, 0);
    }
}

// Round 4
// 397.636 us; speedup vs baseline: 1.7849x; 1.7849x over previous
//
#include <hip/hip_runtime.h>

// ---------------------------------------------------------------------------
// GraphSAGE 2-layer, bf16 + deterministic bucketed CSR build (no global
// atomics anywhere in the partition):
//   hist2:     per-8192-edge chunk LDS histogram of dst>>6 -> cntmat row
//   colscan:   per-bucket column scan of cntmat -> per-chunk prefixes + totals
//   bucket_scan: exclusive scan of totals -> bucket bases
//   partition2: re-read chunk, LDS cursors = base+prefix, LDS-atomic scatter
//               of packed pairs ((dst&63)<<16 | src) into bucket ranges
//   bucket_scatter: 1 wg/bucket, LDS node cursors -> offs/inv_deg/csr
//   agg(xb) -> mean1b ; MFMA gemms ; projection-first layer 2 (unchanged)
// ---------------------------------------------------------------------------

#define IN_DIM 128
#define HID_DIM 256
#define OUT_DIM 128

#define EPB 8192   // edges per chunk
#define NBMAX 784  // max buckets (50000/64 -> 782)

typedef unsigned short u16;
typedef unsigned int u32;
typedef __attribute__((ext_vector_type(8))) short short8;   // 8 bf16 (4 VGPRs)
typedef __attribute__((ext_vector_type(4))) float float4v;  // 4 fp32 acc

static __device__ __forceinline__ u16 f2bf(float f) {
    u32 u = __builtin_bit_cast(u32, f);
    u = (u + 0x7fffu + ((u >> 16) & 1u)) >> 16;
    return (u16)u;
}
static __device__ __forceinline__ float bf2f(u32 lo16) {
    return __builtin_bit_cast(float, lo16 << 16);
}

// -------------------- deterministic bucketed partition --------------------

__global__ __launch_bounds__(256) void hist2(const int* __restrict__ dst,
                                             int n_edges, int nb,
                                             int* __restrict__ cntmat) {
    __shared__ int h[NBMAX];
    int t = threadIdx.x;
    for (int i = t; i < nb; i += 256) h[i] = 0;
    __syncthreads();
    int base = blockIdx.x * EPB;
    int end = min(base + EPB, n_edges);
    for (int i = base + t; i < end; i += 256) atomicAdd(&h[dst[i] >> 6], 1);
    __syncthreads();
    int* row = cntmat + (size_t)blockIdx.x * nb;
    for (int i = t; i < nb; i += 256) row[i] = h[i];
}

// column-wise exclusive scan: cntmat[blk][b] -> prefix within bucket b;
// bcnt[b] = bucket total. One thread per bucket, coalesced row reads.
__global__ __launch_bounds__(256) void colscan(int* __restrict__ cntmat,
                                               int nblk, int nb,
                                               int* __restrict__ bcnt) {
    int b = blockIdx.x * 256 + threadIdx.x;
    if (b >= nb) return;
    int run = 0;
    for (int blk = 0; blk < nblk; blk++) {
        size_t idx = (size_t)blk * nb + b;
        int v = cntmat[idx];
        cntmat[idx] = run;
        run += v;
    }
    bcnt[b] = run;
}

__global__ __launch_bounds__(1024) void bucket_scan(
    const int* __restrict__ bcnt, int nb, int n_edges,
    int* __restrict__ bbase) {
    __shared__ int s[1024];
    int t = threadIdx.x;
    int v = (t < nb) ? bcnt[t] : 0;
    s[t] = v;
    __syncthreads();
    for (int off = 1; off < 1024; off <<= 1) {
        int add = (t >= off) ? s[t - off] : 0;
        __syncthreads();
        s[t] += add;
        __syncthreads();
    }
    if (t < nb) bbase[t] = s[t] - v;
    if (t == 0) bbase[nb] = n_edges;
}

__global__ __launch_bounds__(256) void partition2(
    const int* __restrict__ src, const int* __restrict__ dst, int n_edges,
    int nb, const int* __restrict__ bbase, const int* __restrict__ cntmat,
    u32* __restrict__ pairs) {
    __shared__ int cur[NBMAX];
    int t = threadIdx.x;
    const int* row = cntmat + (size_t)blockIdx.x * nb;
    for (int i = t; i < nb; i += 256) cur[i] = bbase[i] + row[i];
    __syncthreads();
    int base = blockIdx.x * EPB;
    int end = min(base + EPB, n_edges);
    for (int i = base + t; i < end; i += 256) {
        int d = dst[i];
        int pos = atomicAdd(&cur[d >> 6], 1);  // LDS atomic
        pairs[pos] = ((u32)(d & 63) << 16) | (u32)src[i];
    }
}

__global__ __launch_bounds__(256) void bucket_scatter(
    const u32* __restrict__ pairs, const int* __restrict__ bbase,
    int n_nodes, int n_edges,
    int* __restrict__ offs, float* __restrict__ inv_deg,
    int* __restrict__ csr) {
    int b = blockIdx.x;
    int t = threadIdx.x;
    int beg = bbase[b], end = bbase[b + 1];
    __shared__ int cnt[64];
    __shared__ int cur[64];
    if (t < 64) cnt[t] = 0;
    __syncthreads();
    for (int i = beg + t; i < end; i += 256)
        atomicAdd(&cnt[(pairs[i] >> 16) & 63], 1);
    __syncthreads();
    if (t < 64) {  // wave 0: shuffle exclusive scan over 64 node counts
        int v = cnt[t];
        int incl = v;
#pragma unroll
        for (int off = 1; off < 64; off <<= 1) {
            int u = __shfl_up(incl, off, 64);
            if (t >= off) incl += u;
        }
        int o = beg + incl - v;
        int node = b * 64 + t;
        if (node < n_nodes) {
            offs[node] = o;
            inv_deg[node] = 1.0f / (float)(v > 0 ? v : 1);
        }
        cur[t] = o;
    }
    if (b == 0 && t == 0) offs[n_nodes] = n_edges;
    __syncthreads();
    for (int i = beg + t; i < end; i += 256) {
        u32 pr = pairs[i];
        int p = atomicAdd(&cur[(pr >> 16) & 63], 1);
        csr[p] = (int)(pr & 0xffffu);
    }
}

// -------------------- casts --------------------

__global__ void cast_x_kernel(const float* __restrict__ in,
                              u16* __restrict__ out, int n4) {
    int i = blockIdx.x * 256 + threadIdx.x;
    if (i < n4) {
        float4 v = *(const float4*)(in + (size_t)i * 4);
        u32 lo = (u32)f2bf(v.x) | ((u32)f2bf(v.y) << 16);
        u32 hi = (u32)f2bf(v.z) | ((u32)f2bf(v.w) << 16);
        uint2 o;
        o.x = lo;
        o.y = hi;
        *(uint2*)(out + (size_t)i * 4) = o;
    }
}

// in: [R][C] fp32 row-major -> out: [C][R] bf16 row-major
__global__ void transpose_cast_kernel(const float* __restrict__ in,
                                      u16* __restrict__ out, int R, int C) {
    int i = blockIdx.x * 256 + threadIdx.x;
    if (i < R * C) {
        int c = i / R;
        int r = i - c * R;
        out[i] = f2bf(in[(size_t)r * C + c]);
    }
}

// -------------------- mean aggregation (D=128 bf16, 1 wave/node) -----------

__global__ __launch_bounds__(256) void agg_bf16(
    const u16* __restrict__ feat, const int* __restrict__ offs,
    const int* __restrict__ csr, const float* __restrict__ inv_deg,
    int n_nodes, u16* __restrict__ out_bf, float* __restrict__ out_f) {
    int wave = threadIdx.x >> 6;
    int lane = threadIdx.x & 63;
    int node = blockIdx.x * 4 + wave;
    if (node >= n_nodes) return;
    int beg = offs[node], end = offs[node + 1];
    float a0 = 0.f, a1 = 0.f;
    int i = beg;
    for (; i + 8 <= end; i += 8) {
        u32 v[8];
#pragma unroll
        for (int j = 0; j < 8; j++) {
            int s = csr[i + j];
            v[j] = *(const u32*)(feat + (size_t)s * 128 + lane * 2);
        }
#pragma unroll
        for (int j = 0; j < 8; j++) {
            a0 += bf2f(v[j] & 0xffffu);
            a1 += bf2f(v[j] >> 16);
        }
    }
    for (; i < end; i++) {
        int s = csr[i];
        u32 v = *(const u32*)(feat + (size_t)s * 128 + lane * 2);
        a0 += bf2f(v & 0xffffu);
        a1 += bf2f(v >> 16);
    }
    float inv = inv_deg[node];
    a0 *= inv;
    a1 *= inv;
    if (out_bf) {
        u32 pv = (u32)f2bf(a0) | ((u32)f2bf(a1) << 16);
        *(u32*)(out_bf + (size_t)node * 128 + lane * 2) = pv;
    } else {
        float2 o;
        o.x = a0;
        o.y = a1;
        *(float2*)(out_f + (size_t)node * 128 + lane * 2) = o;
    }
}

// -------------------- MFMA GEMM --------------------
// C[M,N] = act( sum_mat A_mat[M,K] @ B_mat[K,N] + bias + addend )
// A bf16 row-major; BT bf16 = B^T [N][K] row-major. Block: 4 waves;
// tile 128(M) x 64(N); wave = 32x64 via 2x4 of 16x16x32 mfma.

__global__ __launch_bounds__(256) void gemm_bf16(
    const u16* __restrict__ A1, const u16* __restrict__ A2,
    const u16* __restrict__ BT1, const u16* __restrict__ BT2,
    const float* __restrict__ bias, const float* __restrict__ addend,
    u16* __restrict__ out_bf, float* __restrict__ out_f,
    int M, int K, int N, int nmat, int relu) {
    extern __shared__ u16 Bs[];
    const int KP = K + 8;
    int t = threadIdx.x;
    int colbase = blockIdx.y * 64;

    int total8 = nmat * 64 * K / 8;
    for (int c = t; c < total8; c += 256) {
        int flat = c * 8;
        int mat = flat / (64 * K);
        int rem = flat - mat * 64 * K;
        int n = rem / K;
        int k = rem - n * K;
        const u16* srcp = (mat ? BT2 : BT1) + (size_t)(colbase + n) * K + k;
        *(uint4*)(&Bs[mat * 64 * KP + n * KP + k]) = *(const uint4*)srcp;
    }
    __syncthreads();

    int lane = t & 63;
    int wave = t >> 6;
    int quad = lane >> 4;
    int l16 = lane & 15;
    int row_base = blockIdx.x * 128 + wave * 32;

    float4v zero = {0.f, 0.f, 0.f, 0.f};
    float4v acc[2][4];
#pragma unroll
    for (int mi = 0; mi < 2; mi++)
#pragma unroll
        for (int ni = 0; ni < 4; ni++) acc[mi][ni] = zero;

    for (int mat = 0; mat < nmat; mat++) {
        const u16* A = mat ? A2 : A1;
        const u16* Bp = &Bs[mat * 64 * KP];
        for (int ks = 0; ks < (K >> 5); ks++) {
            int k = ks * 32 + quad * 8;
            short8 af[2] = {{0, 0, 0, 0, 0, 0, 0, 0}, {0, 0, 0, 0, 0, 0, 0, 0}};
#pragma unroll
            for (int mi = 0; mi < 2; mi++) {
                int m = row_base + mi * 16 + l16;
                if (m < M) af[mi] = *(const short8*)(A + (size_t)m * K + k);
            }
#pragma unroll
            for (int ni = 0; ni < 4; ni++) {
                short8 bfr = *(const short8*)(Bp + (ni * 16 + l16) * KP + k);
                acc[0][ni] = __builtin_amdgcn_mfma_f32_16x16x32_bf16(
                    af[0], bfr, acc[0][ni], 0, 0, 0);
                acc[1][ni] = __builtin_amdgcn_mfma_f32_16x16x32_bf16(
                    af[1], bfr, acc[1][ni], 0, 0, 0);
            }
        }
    }

#pragma unroll
    for (int mi = 0; mi < 2; mi++) {
#pragma unroll
        for (int r = 0; r < 4; r++) {
            int row = row_base + mi * 16 + quad * 4 + r;
            if (row >= M) continue;
#pragma unroll
            for (int ni = 0; ni < 4; ni++) {
                int col = colbase + ni * 16 + l16;
                float v = acc[mi][ni][r];
                if (bias) v += bias[col];
                if (addend) v += addend[(size_t)row * N + col];
                if (relu) v = fmaxf(v, 0.f);
                if (out_bf)
                    out_bf[(size_t)row * N + col] = f2bf(v);
                else
                    out_f[(size_t)row * N + col] = v;
            }
        }
    }
}

// -------------------- launcher --------------------

extern "C" void kernel_launch(void* const* d_in, const int* in_sizes, int n_in,
                              void* d_out, int out_size, void* d_ws, size_t ws_size,
                              hipStream_t stream) {
    const float* x   = (const float*)d_in[0];
    const int*  eidx = (const int*)d_in[1];
    const float* Wl1 = (const float*)d_in[2];
    const float* bl1 = (const float*)d_in[3];
    const float* Wr1 = (const float*)d_in[4];
    const float* Wl2 = (const float*)d_in[5];
    const float* bl2 = (const float*)d_in[6];
    const float* Wr2 = (const float*)d_in[7];

    int n_nodes = in_sizes[0] / IN_DIM;
    int n_edges = in_sizes[1] / 2;
    const int* src = eidx;
    const int* dst = eidx + n_edges;
    int nb = (n_nodes + 63) / 64;            // buckets of 64 nodes
    int nchunk = (n_edges + EPB - 1) / EPB;  // edge chunks

    char* p = (char*)d_ws;
    auto alloc = [&](size_t bytes) {
        void* q = (void*)p;
        p += (bytes + 255) & ~(size_t)255;
        return q;
    };
    int*   bcnt    = (int*)alloc((size_t)(nb + 1) * 4);
    int*   bbase   = (int*)alloc((size_t)(nb + 1) * 4);
    int*   cntmat  = (int*)alloc((size_t)nchunk * nb * 4);
    int*   offs    = (int*)alloc((size_t)(n_nodes + 1) * 4);
    float* inv_deg = (float*)alloc((size_t)n_nodes * 4);
    u32*   pairs   = (u32*)alloc((size_t)n_edges * 4);
    int*   csr     = (int*)alloc((size_t)n_edges * 4);
    u16*   xb      = (u16*)alloc((size_t)n_nodes * IN_DIM * 2);
    u16*   mean1b  = (u16*)alloc((size_t)n_nodes * IN_DIM * 2);
    u16*   hb      = (u16*)alloc((size_t)n_nodes * HID_DIM * 2);
    u16*   pb      = (u16*)alloc((size_t)n_nodes * OUT_DIM * 2);
    float* mean2   = (float*)alloc((size_t)n_nodes * OUT_DIM * 4);
    u16*   WTl1b   = (u16*)alloc((size_t)IN_DIM * HID_DIM * 2);
    u16*   WTr1b   = (u16*)alloc((size_t)IN_DIM * HID_DIM * 2);
    u16*   WTl2b   = (u16*)alloc((size_t)HID_DIM * OUT_DIM * 2);
    u16*   WTr2b   = (u16*)alloc((size_t)HID_DIM * OUT_DIM * 2);

    // deterministic bucketed CSR build (no global atomics)
    hist2<<<nchunk, 256, 0, stream>>>(dst, n_edges, nb, cntmat);
    colscan<<<(nb + 255) / 256, 256, 0, stream>>>(cntmat, nchunk, nb, bcnt);
    bucket_scan<<<1, 1024, 0, stream>>>(bcnt, nb, n_edges, bbase);
    partition2<<<nchunk, 256, 0, stream>>>(src, dst, n_edges, nb, bbase,
                                           cntmat, pairs);
    bucket_scatter<<<nb, 256, 0, stream>>>(pairs, bbase, n_nodes, n_edges,
                                           offs, inv_deg, csr);

    // casts
    int n4 = n_nodes * IN_DIM / 4;
    cast_x_kernel<<<(n4 + 255) / 256, 256, 0, stream>>>(x, xb, n4);
    int wsz = IN_DIM * HID_DIM;
    transpose_cast_kernel<<<(wsz + 255) / 256, 256, 0, stream>>>(Wl1, WTl1b, IN_DIM, HID_DIM);
    transpose_cast_kernel<<<(wsz + 255) / 256, 256, 0, stream>>>(Wr1, WTr1b, IN_DIM, HID_DIM);
    transpose_cast_kernel<<<(wsz + 255) / 256, 256, 0, stream>>>(Wl2, WTl2b, HID_DIM, OUT_DIM);
    transpose_cast_kernel<<<(wsz + 255) / 256, 256, 0, stream>>>(Wr2, WTr2b, HID_DIM, OUT_DIM);

    int gx = (n_nodes + 127) / 128;

    // layer 1: agg x, h = relu(mean1@Wl1 + x@Wr1 + bl1)
    agg_bf16<<<(n_nodes + 3) / 4, 256, 0, stream>>>(xb, offs, csr, inv_deg,
                                                    n_nodes, mean1b, nullptr);
    {
        dim3 g(gx, HID_DIM / 64);
        size_t smem = 2 * 64 * (size_t)(IN_DIM + 8) * 2;
        gemm_bf16<<<g, 256, smem, stream>>>(mean1b, xb, WTl1b, WTr1b, bl1,
                                            nullptr, hb, nullptr,
                                            n_nodes, IN_DIM, HID_DIM, 2, 1);
    }

    // layer 2 projection-first: pb = hb@Wl2
    {
        dim3 g(gx, OUT_DIM / 64);
        size_t smem = 1 * 64 * (size_t)(HID_DIM + 8) * 2;
        gemm_bf16<<<g, 256, smem, stream>>>(hb, nullptr, WTl2b, nullptr,
                                            nullptr, nullptr, pb, nullptr,
                                            n_nodes, HID_DIM, OUT_DIM, 1, 0);
    }
    // mean2 = mean(pb) (fp32)
    agg_bf16<<<(n_nodes + 3) / 4, 256, 0, stream>>>(pb, offs, csr, inv_deg,
                                                    n_nodes, nullptr, mean2);
    // out = hb@Wr2 + bl2 + mean2
    {
        dim3 g(gx, OUT_DIM / 64);
        size_t smem = 1 * 64 * (size_t)(HID_DIM + 8) * 2;
        gemm_bf16<<<g, 256, smem, stream>>>(hb, nullptr, WTr2b, nullptr,
                                            bl2, mean2, nullptr, (float*)d_out,
                                            n_nodes, HID_DIM, OUT_DIM, 1, 0);
    }
}